// Round 1
// baseline (76.911 us; speedup 1.0000x reference)
//
#include <hip/hip_runtime.h>

// out[b, t, c] = data[(index[b] + t) % cycle_len][c]
// B=2048, L=720, C=64 (fp32). Pure write-streaming kernel.
//
// Strategy: one block per batch element b. Stage data (cycle_len x 64 fp32 =
// 43 KB) in LDS once, then stream the 720x64 output rows as coalesced float4
// stores. Row index advances incrementally (+16 mod cycle_len per grid-stride
// step) so we pay exactly one integer mod per thread.

constexpr int CCH   = 64;        // channels
constexpr int C4    = CCH / 4;   // float4 per row = 16
constexpr int BLOCK = 256;

__global__ __launch_bounds__(BLOCK) void recurrent_cycle_kernel(
    const int* __restrict__ index,
    const float4* __restrict__ data4,   // [cycle_len][C4]
    float4* __restrict__ out4,          // [B][L][C4]
    int L, int cycle_len)
{
    extern __shared__ float4 lds[];     // cycle_len * C4 float4s

    const int tid = threadIdx.x;
    const int b   = blockIdx.x;

    // Stage data table into LDS (coalesced float4 loads).
    const int total4 = cycle_len * C4;
    for (int i = tid; i < total4; i += BLOCK)
        lds[i] = data4[i];
    __syncthreads();

    const int idx = index[b];
    float4* outb = out4 + (size_t)b * (size_t)L * C4;
    const int n = L * C4;               // 720*16 = 11520 float4 per batch

    // Thread tid starts at flat float4 position tid: t = tid/16, c4 = tid%15.
    int       t0  = tid >> 4;
    const int c4  = tid & (C4 - 1);
    int row = (idx + t0) % cycle_len;   // the only integer mod
    // Each grid-stride step advances t by BLOCK/C4 = 16 rows.
    const int rstep = (BLOCK / C4) % cycle_len;

    for (int p = tid; p < n; p += BLOCK) {
        outb[p] = lds[row * C4 + c4];
        row += rstep;
        if (row >= cycle_len) row -= cycle_len;
    }
}

extern "C" void kernel_launch(void* const* d_in, const int* in_sizes, int n_in,
                              void* d_out, int out_size, void* d_ws, size_t ws_size,
                              hipStream_t stream) {
    // setup_inputs order: index [B] int32, length (scalar, unused — derived
    // from out_size), data [cycle_len*64] fp32.
    const int*   index = (const int*)d_in[0];
    const float* data  = (const float*)d_in[2];

    const int B         = in_sizes[0];
    const int cycle_len = in_sizes[2] / CCH;      // 168
    const int L         = out_size / (B * CCH);   // 720

    const size_t lds_bytes = (size_t)cycle_len * CCH * sizeof(float); // 43008

    recurrent_cycle_kernel<<<B, BLOCK, lds_bytes, stream>>>(
        index, (const float4*)data, (float4*)d_out, L, cycle_len);
}